// Round 10
// baseline (875.907 us; speedup 1.0000x reference)
//
#include <hip/hip_runtime.h>
#include <stdint.h>

#define BSHIFT 19
#define NBR 1024         // windowed hist buckets (19-bit granularity)
#define BASEB 0x1700     // abs bucket base (mono>>19) — covers all exact keys
#define HS 512
#define HM 511
#define CAP 4096         // selection capacity (sort area)
#define CAPW 6144        // per-row capture capacity in workspace
#define NT 1024          // k_select threads
#define NT1 256          // k_stream threads
#define CH 8             // chunks per row in k_stream
#define CAPTHR 1.75f     // capture threshold (raw-logit space)

typedef unsigned long long ull;

// ---- raw barrier, LDS-ordering only (HW-validated r5/r6/r9) ----
__device__ __forceinline__ void bar_lds() {
    asm volatile("s_waitcnt lgkmcnt(0)" ::: "memory");
    __builtin_amdgcn_s_barrier();
    __builtin_amdgcn_sched_barrier(0);
}
__device__ __forceinline__ void bar_full() {
    asm volatile("s_waitcnt vmcnt(0) lgkmcnt(0)" ::: "memory");
    __builtin_amdgcn_s_barrier();
    __builtin_amdgcn_sched_barrier(0);
}

// ---- monotonic float<->uint mapping ----
__device__ __forceinline__ unsigned mono_u32(float x) {
    unsigned b = __float_as_uint(x);
    return (b & 0x80000000u) ? ~b : (b | 0x80000000u);
}
__device__ __forceinline__ float inv_mono(unsigned u) {
    unsigned b = (u & 0x80000000u) ? (u & 0x7fffffffu) : ~u;
    return __uint_as_float(b);
}
__device__ __forceinline__ int relb(unsigned m) {
    int rel = (int)(m >> BSHIFT) - BASEB;
    return rel < 0 ? 0 : (rel > NBR - 1 ? NBR - 1 : rel);
}

// numpy op order: pen = freq*cnt + pres*(cnt>0); x = (l - pen) / t
__device__ __forceinline__ float compute_x(float l, int cnt,
                                           float pres, float freq, float t) {
    float pen = __fadd_rn(__fmul_rn(freq, (float)cnt), (cnt > 0) ? pres : 0.0f);
    return __fdiv_rn(__fsub_rn(l, pen), t);
}

__device__ __forceinline__ int hash_cnt(unsigned idx, const int* hkey,
                                        const int* hval) {
    unsigned h = (idx * 2654435761u) >> 23;
    while (true) {
        int kk = hkey[h];
        if (kk == (int)idx) return hval[h];
        if (kk == -1) return 0;
        h = (h + 1) & HM;
    }
}

// in-register bitonic stages (r6-validated)
#define SHFL_STAGE(kk, jj) do {                                              \
    int _s = (jj) >> 1;                                                      \
    ull _pA = __shfl_xor(A, _s), _pB = __shfl_xor(B, _s);                    \
    bool _keepmn = (((e0 & (jj)) == 0) == ((e0 & (kk)) != 0));               \
    ull _mnA = (A < _pA) ? A : _pA, _mxA = (A < _pA) ? _pA : A;              \
    ull _mnB = (B < _pB) ? B : _pB, _mxB = (B < _pB) ? _pB : B;              \
    A = _keepmn ? _mnA : _mxA;  B = _keepmn ? _mnB : _mxB;                   \
} while (0)
#define PAIR_STAGE(kk) do {                                                  \
    bool _up = ((e0 & (kk)) != 0);                                           \
    ull _mn = (A < B) ? A : B, _mx = (A < B) ? B : A;                        \
    A = _up ? _mn : _mx;  B = _up ? _mx : _mn;                               \
} while (0)
// paced zero-fill (issued only AFTER all dependent loads — r7/r8 lesson)
#define ZDRIB(nn) do {                                                       \
    for (int _z = 0; _z < (nn) && zc < ZITER; ++_z) {                        \
        int _p = tid + zc * NT; if (_p < V4) o4p[_p] = z4; ++zc;             \
    }                                                                        \
} while (0)

// ================= K0: zero workspace counters =================
__global__ void k_init(float* esum, int* cur, int N) {
    for (int i = threadIdx.x; i < N; i += blockDim.x) { esum[i] = 0.f; cur[i] = 0; }
}

// ================= K1: full-occupancy streaming pass =================
__global__ __launch_bounds__(NT1) void k_stream(
    const float* __restrict__ logits, const float* __restrict__ temps,
    float* __restrict__ esum_ws, int* __restrict__ cur_ws,
    ull* __restrict__ pairs, int capw, int V)
{
    int row = blockIdx.y, c = blockIdx.x, tid = threadIdx.x;
    int V4 = V >> 2;
    int csz = (V4 + CH - 1) / CH;
    int beg = c * csz, end = beg + csz; if (end > V4) end = V4;
    const float* lrow = logits + (size_t)row * V;
    const float4* l4p = (const float4*)lrow;
    ull* prow = pairs + (size_t)row * (size_t)capw;
    float t = temps[row];
    float r = __fdiv_rn(1.0f, t);
    float es = 0.0f;
    int i = beg + tid;
    for (; i + 7 * NT1 < end; i += 8 * NT1) {
        float4 arr[8];
#pragma unroll
        for (int q = 0; q < 8; ++q) arr[q] = l4p[i + q * NT1];
#pragma unroll
        for (int q = 0; q < 8; ++q) {
            int vb = (i + q * NT1) << 2;
#pragma unroll
            for (int j = 0; j < 4; ++j) {
                float l = (&arr[q].x)[j];
                es += __expf(__fmul_rn(l, r));
                if (l >= CAPTHR) {
                    int pos = atomicAdd(&cur_ws[row], 1);
                    if (pos < capw)
                        prow[pos] = ((ull)__float_as_uint(l) << 32) | (unsigned)(vb + j);
                }
            }
        }
    }
    for (; i < end; i += NT1) {
        float4 A4 = l4p[i];
        int vb = i << 2;
#pragma unroll
        for (int j = 0; j < 4; ++j) {
            float l = (&A4.x)[j];
            es += __expf(__fmul_rn(l, r));
            if (l >= CAPTHR) {
                int pos = atomicAdd(&cur_ws[row], 1);
                if (pos < capw)
                    prow[pos] = ((ull)__float_as_uint(l) << 32) | (unsigned)(vb + j);
            }
        }
    }
    if (c == CH - 1) {
        for (int v = (V4 << 2) + tid; v < V; v += NT1) {
            float l = lrow[v];
            es += __expf(__fmul_rn(l, r));
            if (l >= CAPTHR) {
                int pos = atomicAdd(&cur_ws[row], 1);
                if (pos < capw)
                    prow[pos] = ((ull)__float_as_uint(l) << 32) | (unsigned)v;
            }
        }
    }
    for (int off = 32; off; off >>= 1) es += __shfl_down(es, off);
    if ((tid & 63) == 0) atomicAdd(&esum_ws[row], es);
}

// ================= K2: per-row select/sort/scatter + zero-fill =================
__global__ __launch_bounds__(NT) void k_select(
    const float* __restrict__ logits, const int* __restrict__ tokens,
    const float* __restrict__ pres_v, const float* __restrict__ freq_v,
    const float* __restrict__ temps, const float* __restrict__ topp_v,
    const int* __restrict__ topk_v, int V, int H, float* __restrict__ out,
    const float* __restrict__ esum_ws, const int* __restrict__ cur_ws,
    const ull* __restrict__ pairs, int capw)
{
    __shared__ __align__(16) ull sbuf[CAP];      // 32 KB sort area
    __shared__ float se[CAP];                    // 16 KB
    __shared__ unsigned hc[NBR];                 // 4 KB windowed hist
    __shared__ int hkey[HS];                     // 2 KB
    __shared__ int hval[HS];                     // 2 KB
    __shared__ int wt_i[16];
    __shared__ float wt_f[16];
    __shared__ float corr_s;
    __shared__ int bstar_s, lcnt_s;

    int row = blockIdx.x, tid = threadIdx.x;
    int lane = tid & 63, wid = tid >> 6;
    hc[tid] = 0u;                                // NBR == NT
    if (tid == 0) { corr_s = 0.f; bstar_s = -1; lcnt_s = 0; }
    for (int i = tid; i < HS; i += NT) { hkey[i] = -1; hval[i] = 0; }
    __syncthreads();

    // ---- hash of penalty tokens ----
    const int* trow = tokens + (size_t)row * H;
    for (int i = tid; i < H; i += NT) {
        int v = trow[i];
        unsigned h = ((unsigned)v * 2654435761u) >> 23;
        while (true) {
            int prev = atomicCAS(&hkey[h], -1, v);
            if (prev == -1 || prev == v) { atomicAdd(&hval[h], 1); break; }
            h = (h + 1) & HM;
        }
    }
    __syncthreads();

    // ---- row scalars + ALL dependent global loads BEFORE any zero-store ----
    float t = temps[row], topp = topp_v[row];
    float pres = pres_v[row], freq = freq_v[row];
    int k = topk_v[row];
    int active = (pres >= 1e-5f) || (freq >= 1e-5f);
    float r = __fdiv_rn(1.0f, t);
    const float* lrow = logits + (size_t)row * V;
    float4* o4p = (float4*)(out + (size_t)row * V);
    const float4 z4 = make_float4(0.f, 0.f, 0.f, 0.f);
    int V4 = V >> 2;
    int ZITER = (V4 + NT - 1) / NT;
    int zc = 0;
    float esv = esum_ws[row];
    int raw = cur_ws[row];
    int ccount = raw < capw ? raw : capw;
    const ull* prow = pairs + (size_t)row * (size_t)capw;

    // pair loads issued early (coalesced; consumed after corr)
    ull pr[6];
#pragma unroll
    for (int q = 0; q < 6; ++q) {
        int j2 = tid + q * NT;
        pr[q] = (j2 < ccount) ? prow[j2] : 0xffffffffffffffffull;
    }

    // corr: exp-sum correction for penalized tokens (scattered L3-hot loads)
    float corr = 0.0f;
    if (active) {
        for (int s = tid; s < HS; s += NT) {
            int v = hkey[s];
            if (v >= 0) {
                int c = hval[s];
                float l = lrow[v];
                corr += __expf(compute_x(l, c, pres, freq, t))
                      - __expf(__fmul_rn(l, r));
            }
        }
    }
    for (int off = 32; off; off >>= 1) corr += __shfl_down(corr, off);
    if ((tid & 63) == 0) atomicAdd(&corr_s, corr);
    __syncthreads();

    // ---- exact penalized keys + windowed hist; zero-fill dribble starts ----
    ull sk[6]; int rel6[6];
#pragma unroll
    for (int q = 0; q < 6; ++q) {
        if (pr[q] != 0xffffffffffffffffull) {
            unsigned idx = (unsigned)(pr[q] & 0xffffffffull);
            float l = __uint_as_float((unsigned)(pr[q] >> 32));
            int c = active ? hash_cnt(idx, hkey, hval) : 0;
            float xe = (c > 0) ? compute_x(l, c, pres, freq, t) : __fdiv_rn(l, t);
            unsigned ue = mono_u32(xe);
            int rl = relb(ue);
            atomicAdd(&hc[rl], 1u);
            sk[q] = ((ull)ue << 32) | (unsigned)~idx;
            rel6[q] = rl;
        } else { sk[q] = 0ull; rel6[q] = -1; }
    }
    ZDRIB(2); bar_lds();

    // ---- cut: suffix scan over windowed hist (1 bucket/thread) ----
    int myc = (int)hc[tid];
    int vs = myc;
#pragma unroll
    for (int off = 1; off < 64; off <<= 1) {
        int o = __shfl_down(vs, off);
        if (lane + off < 64) vs += o;
    }
    if (lane == 0) wt_i[wid] = vs;
    ZDRIB(2); bar_lds();
    int tot = 0;
#pragma unroll
    for (int w = 0; w < 16; ++w) tot += wt_i[w];
    int above = vs - myc;
#pragma unroll
    for (int w = 0; w < 16; ++w) if (w > wid) above += wt_i[w];
    int fb = (tot < k) || (raw > capw) || (capw <= 0);   // block-uniform
    if (!fb && (myc + above >= k)) atomicMax(&bstar_s, tid);
    ZDRIB(2); bar_lds();
    int bst_rel = bstar_s < 0 ? 0 : bstar_s;
    int lb_rel = relb(mono_u32(__fdiv_rn(CAPTHR, t)));
    bool skip = (!fb) && (lb_rel < bst_rel);   // non-captured provably below cut
    float Sp = esv + corr_s;
    int count;

    if (skip) {
        // in-register filter + ordered block compaction
        int sb[6], svc = 0;
#pragma unroll
        for (int q = 0; q < 6; ++q) { sb[q] = (rel6[q] >= bst_rel) ? 1 : 0; svc += sb[q]; }
        int vp = svc;
#pragma unroll
        for (int off = 1; off < 64; off <<= 1) {
            int o = __shfl_up(vp, off);
            if (lane >= off) vp += o;
        }
        if (lane == 63) wt_i[wid] = vp;
        ZDRIB(2); bar_lds();
        int pre = vp - svc;
#pragma unroll
        for (int w = 0; w < 16; ++w) if (w < wid) pre += wt_i[w];
        int total = 0;
#pragma unroll
        for (int w = 0; w < 16; ++w) total += wt_i[w];
        int pos = pre;
#pragma unroll
        for (int q = 0; q < 6; ++q)
            if (sb[q]) { if (pos < CAP) sbuf[pos] = sk[q]; ++pos; }
        count = total > CAP ? CAP : total;
        ZDRIB(2); bar_lds();
    } else {
        // full fallback: rebuild exact-key hist over all V, re-cut, re-filter
        if (tid == 0) bstar_s = -1;
        hc[tid] = 0u;
        bar_lds();
        for (int v = tid; v < V; v += NT) {
            float l = lrow[v];
            int c = active ? hash_cnt((unsigned)v, hkey, hval) : 0;
            float xe = (c > 0) ? compute_x(l, c, pres, freq, t) : __fdiv_rn(l, t);
            atomicAdd(&hc[relb(mono_u32(xe))], 1u);
        }
        bar_lds();
        myc = (int)hc[tid];
        vs = myc;
#pragma unroll
        for (int off = 1; off < 64; off <<= 1) {
            int o = __shfl_down(vs, off);
            if (lane + off < 64) vs += o;
        }
        if (lane == 0) wt_i[wid] = vs;
        bar_lds();
        above = vs - myc;
#pragma unroll
        for (int w = 0; w < 16; ++w) if (w > wid) above += wt_i[w];
        if (myc + above >= k) atomicMax(&bstar_s, tid);
        bar_lds();
        bst_rel = bstar_s < 0 ? 0 : bstar_s;
        for (int v = tid; v < V; v += NT) {
            float l = lrow[v];
            int c = active ? hash_cnt((unsigned)v, hkey, hval) : 0;
            float xe = (c > 0) ? compute_x(l, c, pres, freq, t) : __fdiv_rn(l, t);
            unsigned ue = mono_u32(xe);
            if (relb(ue) >= bst_rel) {
                int pos = atomicAdd(&lcnt_s, 1);
                if (pos < CAP) sbuf[pos] = ((ull)ue << 32) | (unsigned)~(unsigned)v;
            }
        }
        bar_lds();
        count = lcnt_s > CAP ? CAP : lcnt_s;
    }

    // ---- bitonic sort descending ----
    if (count <= 2048) {
        const int M = 2048;
        for (int j = count + tid; j < M; j += NT) sbuf[j] = 0ull;
        ZDRIB(2); bar_lds();
        int e0 = (wid << 7) + (lane << 1);
        ull A = sbuf[e0], B = sbuf[e0 + 1];
        ZDRIB(2);
        for (int kk = 2; kk <= 128; kk <<= 1) {      // register levels, 0 barriers
            for (int jj = kk >> 1; jj >= 2; jj >>= 1) SHFL_STAGE(kk, jj);
            PAIR_STAGE(kk);
        }
        for (int kk = 256; kk <= 2048; kk <<= 1) {   // cross-wave stages in LDS
            sbuf[e0] = A; sbuf[e0 + 1] = B;
            ZDRIB(2); bar_lds();
            for (int jj = kk >> 1; jj >= 128; jj >>= 1) {
                for (int i2 = tid; i2 < M; i2 += NT) {
                    int ixj = i2 ^ jj;
                    if (ixj > i2) {
                        ull X = sbuf[i2], Y = sbuf[ixj];
                        bool up = ((i2 & kk) != 0);
                        if ((X > Y) == up) { sbuf[i2] = Y; sbuf[ixj] = X; }
                    }
                }
                ZDRIB(2); bar_lds();
            }
            A = sbuf[e0]; B = sbuf[e0 + 1];
            for (int jj = 64; jj >= 2; jj >>= 1) SHFL_STAGE(kk, jj);
            PAIR_STAGE(kk);
        }
        sbuf[e0] = A; sbuf[e0 + 1] = B;
    } else {
        int m = 1; while (m < count) m <<= 1;
        for (int j = count + tid; j < m; j += NT) sbuf[j] = 0ull;
        bar_lds();
        for (int kk = 2; kk <= m; kk <<= 1) {
            for (int jj = kk >> 1; jj > 0; jj >>= 1) {
                for (int i2 = tid; i2 < m; i2 += NT) {
                    int ixj = i2 ^ jj;
                    if (ixj > i2) {
                        ull X = sbuf[i2], Y = sbuf[ixj];
                        bool up = ((i2 & kk) != 0);
                        if ((X > Y) == up) { sbuf[i2] = Y; sbuf[ixj] = X; }
                    }
                }
                bar_lds();
            }
        }
    }

    // catch-up zero-fill (fire-and-forget; drained by bar_full before scatter)
    for (; zc < ZITER; ++zc) {
        int p = tid + zc * NT;
        if (p < V4) o4p[p] = z4;
    }
    for (int v2 = (V4 << 2) + tid; v2 < V; v2 += NT)
        out[(size_t)row * V + v2] = 0.0f;
    bar_lds();                                       // publish sbuf final state

    // ---- phase F: exp, exact cumsum, select, scatter ----
    for (int j = tid; j < CAP; j += NT)
        se[j] = (j < count) ? __expf(inv_mono((unsigned)(sbuf[j] >> 32))) : 0.0f;
    bar_lds();
    int j0 = tid << 2;
    float e0f = se[j0], e1 = se[j0 + 1], e2 = se[j0 + 2], e3 = se[j0 + 3];
    float c0 = e0f, c1 = c0 + e1, c2 = c1 + e2, c3 = c2 + e3;
    float vf = c3;
#pragma unroll
    for (int off = 1; off < 64; off <<= 1) {
        float o = __shfl_up(vf, off);
        if (lane >= off) vf += o;
    }
    if (lane == 63) wt_f[wid] = vf;
    bar_lds();
    float pre = vf - c3;
#pragma unroll
    for (int w = 0; w < 16; ++w) if (w < wid) pre += wt_f[w];

    bar_full();                                      // zero-stores before scatter

    float pS = topp * Sp;
    float inc[4] = {pre + c0, pre + c1, pre + c2, pre + c3};
    float ee[4] = {e0f, e1, e2, e3};
#pragma unroll
    for (int q = 0; q < 4; ++q) {
        int j = j0 + q;
        if (j < count) {
            float e = ee[q];
            float excl = __fsub_rn(inc[q], e);
            if ((j < k) && (excl <= pS)) {
                unsigned idx = ~(unsigned)(sbuf[j] & 0xffffffffull);
                out[(size_t)row * V + idx] = __fdiv_rn(e, Sp);
            }
        }
    }
}

extern "C" void kernel_launch(void* const* d_in, const int* in_sizes, int n_in,
                              void* d_out, int out_size, void* d_ws, size_t ws_size,
                              hipStream_t stream) {
    const float* logits = (const float*)d_in[0];
    const float* pres   = (const float*)d_in[1];
    const float* freq   = (const float*)d_in[2];
    const float* temps  = (const float*)d_in[3];
    const float* topps  = (const float*)d_in[4];
    const int*   tokens = (const int*)d_in[5];
    const int*   topks  = (const int*)d_in[6];
    int N = in_sizes[1];
    int V = in_sizes[0] / N;
    int H = in_sizes[5] / N;
    float* out = (float*)d_out;

    size_t A = ((size_t)N * 4 + 255) & ~(size_t)255;
    float* esum_ws = (float*)d_ws;
    int*   cur_ws  = (int*)((char*)d_ws + A);
    ull*   pairs   = (ull*)((char*)d_ws + 2 * A);
    int capw = 0;
    if (ws_size > 2 * A + 8)
        capw = (int)(((ws_size - 2 * A) / 8) / (size_t)N);
    if (capw > CAPW) capw = CAPW;
    if (capw < 0) capw = 0;

    k_init<<<1, 256, 0, stream>>>(esum_ws, cur_ws, N);
    k_stream<<<dim3(CH, N), NT1, 0, stream>>>(logits, temps, esum_ws, cur_ws,
                                              pairs, capw, V);
    k_select<<<N, NT, 0, stream>>>(logits, tokens, pres, freq, temps, topps,
                                   topks, V, H, out, esum_ws, cur_ws, pairs, capw);
}

// Round 11
// 282.549 us; speedup vs baseline: 3.1000x; 3.1000x over previous
//
#include <hip/hip_runtime.h>
#include <stdint.h>

#define BSHIFT 19
#define NBR 1024         // windowed hist buckets (19-bit granularity)
#define BASEB 0x1700     // abs bucket base (mono>>19) — covers all exact keys
#define HS 512
#define HM 511
#define CAP 4096         // selection capacity (sort area)
#define CAPW 6144        // per-row capture capacity in workspace
#define NT 1024          // k_select threads
#define NT1 256          // k_stream threads
#define CH 8             // chunks per row in k_stream
#define LCAP 1536        // per-block local capture capacity (12 KB LDS)
#define CAPTHR 1.75f     // capture threshold (raw-logit space)

typedef unsigned long long ull;

// ---- raw barrier, LDS-ordering only (HW-validated r5/r6/r9) ----
__device__ __forceinline__ void bar_lds() {
    asm volatile("s_waitcnt lgkmcnt(0)" ::: "memory");
    __builtin_amdgcn_s_barrier();
    __builtin_amdgcn_sched_barrier(0);
}
__device__ __forceinline__ void bar_full() {
    asm volatile("s_waitcnt vmcnt(0) lgkmcnt(0)" ::: "memory");
    __builtin_amdgcn_s_barrier();
    __builtin_amdgcn_sched_barrier(0);
}

// ---- monotonic float<->uint mapping ----
__device__ __forceinline__ unsigned mono_u32(float x) {
    unsigned b = __float_as_uint(x);
    return (b & 0x80000000u) ? ~b : (b | 0x80000000u);
}
__device__ __forceinline__ float inv_mono(unsigned u) {
    unsigned b = (u & 0x80000000u) ? (u & 0x7fffffffu) : ~u;
    return __uint_as_float(b);
}
__device__ __forceinline__ int relb(unsigned m) {
    int rel = (int)(m >> BSHIFT) - BASEB;
    return rel < 0 ? 0 : (rel > NBR - 1 ? NBR - 1 : rel);
}

// numpy op order: pen = freq*cnt + pres*(cnt>0); x = (l - pen) / t
__device__ __forceinline__ float compute_x(float l, int cnt,
                                           float pres, float freq, float t) {
    float pen = __fadd_rn(__fmul_rn(freq, (float)cnt), (cnt > 0) ? pres : 0.0f);
    return __fdiv_rn(__fsub_rn(l, pen), t);
}

__device__ __forceinline__ int hash_cnt(unsigned idx, const int* hkey,
                                        const int* hval) {
    unsigned h = (idx * 2654435761u) >> 23;
    while (true) {
        int kk = hkey[h];
        if (kk == (int)idx) return hval[h];
        if (kk == -1) return 0;
        h = (h + 1) & HM;
    }
}

// in-register bitonic stages (r6-validated)
#define SHFL_STAGE(kk, jj) do {                                              \
    int _s = (jj) >> 1;                                                      \
    ull _pA = __shfl_xor(A, _s), _pB = __shfl_xor(B, _s);                    \
    bool _keepmn = (((e0 & (jj)) == 0) == ((e0 & (kk)) != 0));               \
    ull _mnA = (A < _pA) ? A : _pA, _mxA = (A < _pA) ? _pA : A;              \
    ull _mnB = (B < _pB) ? B : _pB, _mxB = (B < _pB) ? _pB : B;              \
    A = _keepmn ? _mnA : _mxA;  B = _keepmn ? _mnB : _mxB;                   \
} while (0)
#define PAIR_STAGE(kk) do {                                                  \
    bool _up = ((e0 & (kk)) != 0);                                           \
    ull _mn = (A < B) ? A : B, _mx = (A < B) ? B : A;                        \
    A = _up ? _mn : _mx;  B = _up ? _mx : _mn;                               \
} while (0)
// paced zero-fill (issued only AFTER all dependent loads — r7/r8 lesson)
#define ZDRIB(nn) do {                                                       \
    for (int _z = 0; _z < (nn) && zc < ZITER; ++_z) {                        \
        int _p = tid + zc * NT; if (_p < V4) o4p[_p] = z4; ++zc;             \
    }                                                                        \
} while (0)

// ================= K0: zero workspace counters =================
__global__ void k_init(float* esum, int* cur, int N) {
    for (int i = threadIdx.x; i < N; i += blockDim.x) { esum[i] = 0.f; cur[i] = 0; }
}

// ================= K1: full-occupancy streaming pass =================
// Capture goes to an LDS staging buffer (block-local atomics), then ONE
// global atomicAdd per block reserves a range in the per-row list (r10
// lesson: a per-element global atomic chain on one address = ~128ns/op
// serialized critical path = 656us).
__global__ __launch_bounds__(NT1) void k_stream(
    const float* __restrict__ logits, const float* __restrict__ temps,
    float* __restrict__ esum_ws, int* __restrict__ cur_ws,
    ull* __restrict__ pairs, int capw, int V)
{
    __shared__ ull lbuf[LCAP];                  // 12 KB local capture
    __shared__ int lcnt_s, base_s;
    int row = blockIdx.y, c = blockIdx.x, tid = threadIdx.x;
    if (tid == 0) lcnt_s = 0;
    __syncthreads();

    int V4 = V >> 2;
    int csz = (V4 + CH - 1) / CH;
    int beg = c * csz, end = beg + csz; if (end > V4) end = V4;
    const float* lrow = logits + (size_t)row * V;
    const float4* l4p = (const float4*)lrow;
    ull* prow = pairs + (size_t)row * (size_t)capw;
    float t = temps[row];
    float r = __fdiv_rn(1.0f, t);
    float es = 0.0f;
    int i = beg + tid;
    for (; i + 7 * NT1 < end; i += 8 * NT1) {
        float4 arr[8];
#pragma unroll
        for (int q = 0; q < 8; ++q) arr[q] = l4p[i + q * NT1];
#pragma unroll
        for (int q = 0; q < 8; ++q) {
            int vb = (i + q * NT1) << 2;
#pragma unroll
            for (int j = 0; j < 4; ++j) {
                float l = (&arr[q].x)[j];
                es += __expf(__fmul_rn(l, r));
                if (l >= CAPTHR) {
                    int pos = atomicAdd(&lcnt_s, 1);   // LDS atomic: block-local
                    if (pos < LCAP)
                        lbuf[pos] = ((ull)__float_as_uint(l) << 32) | (unsigned)(vb + j);
                }
            }
        }
    }
    for (; i < end; i += NT1) {
        float4 A4 = l4p[i];
        int vb = i << 2;
#pragma unroll
        for (int j = 0; j < 4; ++j) {
            float l = (&A4.x)[j];
            es += __expf(__fmul_rn(l, r));
            if (l >= CAPTHR) {
                int pos = atomicAdd(&lcnt_s, 1);
                if (pos < LCAP)
                    lbuf[pos] = ((ull)__float_as_uint(l) << 32) | (unsigned)(vb + j);
            }
        }
    }
    if (c == CH - 1) {
        for (int v = (V4 << 2) + tid; v < V; v += NT1) {
            float l = lrow[v];
            es += __expf(__fmul_rn(l, r));
            if (l >= CAPTHR) {
                int pos = atomicAdd(&lcnt_s, 1);
                if (pos < LCAP)
                    lbuf[pos] = ((ull)__float_as_uint(l) << 32) | (unsigned)v;
            }
        }
    }
    for (int off = 32; off; off >>= 1) es += __shfl_down(es, off);
    if ((tid & 63) == 0) atomicAdd(&esum_ws[row], es);
    __syncthreads();

    int lc = lcnt_s;
    int wr = lc > LCAP ? LCAP : lc;
    if (tid == 0) {
        // poison the row cursor on local overflow so k_select takes the
        // full-rescan fallback (raw > capw)
        int add = (lc > LCAP) ? (lc + (1 << 20)) : lc;
        base_s = atomicAdd(&cur_ws[row], add);      // ONE global atomic/block
    }
    __syncthreads();
    int base = base_s;
    for (int j = tid; j < wr; j += NT1) {           // coalesced LDS -> global
        int pos = base + j;
        if (pos < capw) prow[pos] = lbuf[j];
    }
}

// ================= K2: per-row select/sort/scatter + zero-fill =================
__global__ __launch_bounds__(NT) void k_select(
    const float* __restrict__ logits, const int* __restrict__ tokens,
    const float* __restrict__ pres_v, const float* __restrict__ freq_v,
    const float* __restrict__ temps, const float* __restrict__ topp_v,
    const int* __restrict__ topk_v, int V, int H, float* __restrict__ out,
    const float* __restrict__ esum_ws, const int* __restrict__ cur_ws,
    const ull* __restrict__ pairs, int capw)
{
    __shared__ __align__(16) ull sbuf[CAP];      // 32 KB sort area
    __shared__ float se[CAP];                    // 16 KB
    __shared__ unsigned hc[NBR];                 // 4 KB windowed hist
    __shared__ int hkey[HS];                     // 2 KB
    __shared__ int hval[HS];                     // 2 KB
    __shared__ int wt_i[16];
    __shared__ float wt_f[16];
    __shared__ float corr_s;
    __shared__ int bstar_s, lcnt_s;

    int row = blockIdx.x, tid = threadIdx.x;
    int lane = tid & 63, wid = tid >> 6;
    hc[tid] = 0u;                                // NBR == NT
    if (tid == 0) { corr_s = 0.f; bstar_s = -1; lcnt_s = 0; }
    for (int i = tid; i < HS; i += NT) { hkey[i] = -1; hval[i] = 0; }
    __syncthreads();

    // ---- hash of penalty tokens ----
    const int* trow = tokens + (size_t)row * H;
    for (int i = tid; i < H; i += NT) {
        int v = trow[i];
        unsigned h = ((unsigned)v * 2654435761u) >> 23;
        while (true) {
            int prev = atomicCAS(&hkey[h], -1, v);
            if (prev == -1 || prev == v) { atomicAdd(&hval[h], 1); break; }
            h = (h + 1) & HM;
        }
    }
    __syncthreads();

    // ---- row scalars + ALL dependent global loads BEFORE any zero-store ----
    float t = temps[row], topp = topp_v[row];
    float pres = pres_v[row], freq = freq_v[row];
    int k = topk_v[row];
    int active = (pres >= 1e-5f) || (freq >= 1e-5f);
    float r = __fdiv_rn(1.0f, t);
    const float* lrow = logits + (size_t)row * V;
    float4* o4p = (float4*)(out + (size_t)row * V);
    const float4 z4 = make_float4(0.f, 0.f, 0.f, 0.f);
    int V4 = V >> 2;
    int ZITER = (V4 + NT - 1) / NT;
    int zc = 0;
    float esv = esum_ws[row];
    int raw = cur_ws[row];
    int ccount = raw < capw ? raw : capw;
    const ull* prow = pairs + (size_t)row * (size_t)capw;

    // pair loads issued early (coalesced; consumed after corr)
    ull pr[6];
#pragma unroll
    for (int q = 0; q < 6; ++q) {
        int j2 = tid + q * NT;
        pr[q] = (j2 < ccount) ? prow[j2] : 0xffffffffffffffffull;
    }

    // corr: exp-sum correction for penalized tokens (scattered L3-hot loads)
    float corr = 0.0f;
    if (active) {
        for (int s = tid; s < HS; s += NT) {
            int v = hkey[s];
            if (v >= 0) {
                int c = hval[s];
                float l = lrow[v];
                corr += __expf(compute_x(l, c, pres, freq, t))
                      - __expf(__fmul_rn(l, r));
            }
        }
    }
    for (int off = 32; off; off >>= 1) corr += __shfl_down(corr, off);
    if ((tid & 63) == 0) atomicAdd(&corr_s, corr);
    __syncthreads();

    // ---- exact penalized keys + windowed hist; zero-fill dribble starts ----
    ull sk[6]; int rel6[6];
#pragma unroll
    for (int q = 0; q < 6; ++q) {
        if (pr[q] != 0xffffffffffffffffull) {
            unsigned idx = (unsigned)(pr[q] & 0xffffffffull);
            float l = __uint_as_float((unsigned)(pr[q] >> 32));
            int c = active ? hash_cnt(idx, hkey, hval) : 0;
            float xe = (c > 0) ? compute_x(l, c, pres, freq, t) : __fdiv_rn(l, t);
            unsigned ue = mono_u32(xe);
            int rl = relb(ue);
            atomicAdd(&hc[rl], 1u);
            sk[q] = ((ull)ue << 32) | (unsigned)~idx;
            rel6[q] = rl;
        } else { sk[q] = 0ull; rel6[q] = -1; }
    }
    ZDRIB(2); bar_lds();

    // ---- cut: suffix scan over windowed hist (1 bucket/thread) ----
    int myc = (int)hc[tid];
    int vs = myc;
#pragma unroll
    for (int off = 1; off < 64; off <<= 1) {
        int o = __shfl_down(vs, off);
        if (lane + off < 64) vs += o;
    }
    if (lane == 0) wt_i[wid] = vs;
    ZDRIB(2); bar_lds();
    int tot = 0;
#pragma unroll
    for (int w = 0; w < 16; ++w) tot += wt_i[w];
    int above = vs - myc;
#pragma unroll
    for (int w = 0; w < 16; ++w) if (w > wid) above += wt_i[w];
    int fb = (tot < k) || (raw > capw) || (capw <= 0);   // block-uniform
    if (!fb && (myc + above >= k)) atomicMax(&bstar_s, tid);
    ZDRIB(2); bar_lds();
    int bst_rel = bstar_s < 0 ? 0 : bstar_s;
    int lb_rel = relb(mono_u32(__fdiv_rn(CAPTHR, t)));
    bool skip = (!fb) && (lb_rel < bst_rel);   // non-captured provably below cut
    float Sp = esv + corr_s;
    int count;

    if (skip) {
        // in-register filter + ordered block compaction
        int sb[6], svc = 0;
#pragma unroll
        for (int q = 0; q < 6; ++q) { sb[q] = (rel6[q] >= bst_rel) ? 1 : 0; svc += sb[q]; }
        int vp = svc;
#pragma unroll
        for (int off = 1; off < 64; off <<= 1) {
            int o = __shfl_up(vp, off);
            if (lane >= off) vp += o;
        }
        if (lane == 63) wt_i[wid] = vp;
        ZDRIB(2); bar_lds();
        int pre = vp - svc;
#pragma unroll
        for (int w = 0; w < 16; ++w) if (w < wid) pre += wt_i[w];
        int total = 0;
#pragma unroll
        for (int w = 0; w < 16; ++w) total += wt_i[w];
        int pos = pre;
#pragma unroll
        for (int q = 0; q < 6; ++q)
            if (sb[q]) { if (pos < CAP) sbuf[pos] = sk[q]; ++pos; }
        count = total > CAP ? CAP : total;
        ZDRIB(2); bar_lds();
    } else {
        // full fallback: rebuild exact-key hist over all V, re-cut, re-filter
        if (tid == 0) bstar_s = -1;
        hc[tid] = 0u;
        bar_lds();
        for (int v = tid; v < V; v += NT) {
            float l = lrow[v];
            int c = active ? hash_cnt((unsigned)v, hkey, hval) : 0;
            float xe = (c > 0) ? compute_x(l, c, pres, freq, t) : __fdiv_rn(l, t);
            atomicAdd(&hc[relb(mono_u32(xe))], 1u);
        }
        bar_lds();
        myc = (int)hc[tid];
        vs = myc;
#pragma unroll
        for (int off = 1; off < 64; off <<= 1) {
            int o = __shfl_down(vs, off);
            if (lane + off < 64) vs += o;
        }
        if (lane == 0) wt_i[wid] = vs;
        bar_lds();
        above = vs - myc;
#pragma unroll
        for (int w = 0; w < 16; ++w) if (w > wid) above += wt_i[w];
        if (myc + above >= k) atomicMax(&bstar_s, tid);
        bar_lds();
        bst_rel = bstar_s < 0 ? 0 : bstar_s;
        for (int v = tid; v < V; v += NT) {
            float l = lrow[v];
            int c = active ? hash_cnt((unsigned)v, hkey, hval) : 0;
            float xe = (c > 0) ? compute_x(l, c, pres, freq, t) : __fdiv_rn(l, t);
            unsigned ue = mono_u32(xe);
            if (relb(ue) >= bst_rel) {
                int pos = atomicAdd(&lcnt_s, 1);
                if (pos < CAP) sbuf[pos] = ((ull)ue << 32) | (unsigned)~(unsigned)v;
            }
        }
        bar_lds();
        count = lcnt_s > CAP ? CAP : lcnt_s;
    }

    // ---- bitonic sort descending ----
    if (count <= 2048) {
        const int M = 2048;
        for (int j = count + tid; j < M; j += NT) sbuf[j] = 0ull;
        ZDRIB(2); bar_lds();
        int e0 = (wid << 7) + (lane << 1);
        ull A = sbuf[e0], B = sbuf[e0 + 1];
        ZDRIB(2);
        for (int kk = 2; kk <= 128; kk <<= 1) {      // register levels, 0 barriers
            for (int jj = kk >> 1; jj >= 2; jj >>= 1) SHFL_STAGE(kk, jj);
            PAIR_STAGE(kk);
        }
        for (int kk = 256; kk <= 2048; kk <<= 1) {   // cross-wave stages in LDS
            sbuf[e0] = A; sbuf[e0 + 1] = B;
            ZDRIB(2); bar_lds();
            for (int jj = kk >> 1; jj >= 128; jj >>= 1) {
                for (int i2 = tid; i2 < M; i2 += NT) {
                    int ixj = i2 ^ jj;
                    if (ixj > i2) {
                        ull X = sbuf[i2], Y = sbuf[ixj];
                        bool up = ((i2 & kk) != 0);
                        if ((X > Y) == up) { sbuf[i2] = Y; sbuf[ixj] = X; }
                    }
                }
                ZDRIB(2); bar_lds();
            }
            A = sbuf[e0]; B = sbuf[e0 + 1];
            for (int jj = 64; jj >= 2; jj >>= 1) SHFL_STAGE(kk, jj);
            PAIR_STAGE(kk);
        }
        sbuf[e0] = A; sbuf[e0 + 1] = B;
    } else {
        int m = 1; while (m < count) m <<= 1;
        for (int j = count + tid; j < m; j += NT) sbuf[j] = 0ull;
        bar_lds();
        for (int kk = 2; kk <= m; kk <<= 1) {
            for (int jj = kk >> 1; jj > 0; jj >>= 1) {
                for (int i2 = tid; i2 < m; i2 += NT) {
                    int ixj = i2 ^ jj;
                    if (ixj > i2) {
                        ull X = sbuf[i2], Y = sbuf[ixj];
                        bool up = ((i2 & kk) != 0);
                        if ((X > Y) == up) { sbuf[i2] = Y; sbuf[ixj] = X; }
                    }
                }
                bar_lds();
            }
        }
    }

    // catch-up zero-fill (fire-and-forget; drained by bar_full before scatter)
    for (; zc < ZITER; ++zc) {
        int p = tid + zc * NT;
        if (p < V4) o4p[p] = z4;
    }
    for (int v2 = (V4 << 2) + tid; v2 < V; v2 += NT)
        out[(size_t)row * V + v2] = 0.0f;
    bar_lds();                                       // publish sbuf final state

    // ---- phase F: exp, exact cumsum, select, scatter ----
    for (int j = tid; j < CAP; j += NT)
        se[j] = (j < count) ? __expf(inv_mono((unsigned)(sbuf[j] >> 32))) : 0.0f;
    bar_lds();
    int j0 = tid << 2;
    float e0f = se[j0], e1 = se[j0 + 1], e2 = se[j0 + 2], e3 = se[j0 + 3];
    float c0 = e0f, c1 = c0 + e1, c2 = c1 + e2, c3 = c2 + e3;
    float vf = c3;
#pragma unroll
    for (int off = 1; off < 64; off <<= 1) {
        float o = __shfl_up(vf, off);
        if (lane >= off) vf += o;
    }
    if (lane == 63) wt_f[wid] = vf;
    bar_lds();
    float pre = vf - c3;
#pragma unroll
    for (int w = 0; w < 16; ++w) if (w < wid) pre += wt_f[w];

    bar_full();                                      // zero-stores before scatter

    float pS = topp * Sp;
    float inc[4] = {pre + c0, pre + c1, pre + c2, pre + c3};
    float ee[4] = {e0f, e1, e2, e3};
#pragma unroll
    for (int q = 0; q < 4; ++q) {
        int j = j0 + q;
        if (j < count) {
            float e = ee[q];
            float excl = __fsub_rn(inc[q], e);
            if ((j < k) && (excl <= pS)) {
                unsigned idx = ~(unsigned)(sbuf[j] & 0xffffffffull);
                out[(size_t)row * V + idx] = __fdiv_rn(e, Sp);
            }
        }
    }
}

extern "C" void kernel_launch(void* const* d_in, const int* in_sizes, int n_in,
                              void* d_out, int out_size, void* d_ws, size_t ws_size,
                              hipStream_t stream) {
    const float* logits = (const float*)d_in[0];
    const float* pres   = (const float*)d_in[1];
    const float* freq   = (const float*)d_in[2];
    const float* temps  = (const float*)d_in[3];
    const float* topps  = (const float*)d_in[4];
    const int*   tokens = (const int*)d_in[5];
    const int*   topks  = (const int*)d_in[6];
    int N = in_sizes[1];
    int V = in_sizes[0] / N;
    int H = in_sizes[5] / N;
    float* out = (float*)d_out;

    size_t A = ((size_t)N * 4 + 255) & ~(size_t)255;
    float* esum_ws = (float*)d_ws;
    int*   cur_ws  = (int*)((char*)d_ws + A);
    ull*   pairs   = (ull*)((char*)d_ws + 2 * A);
    int capw = 0;
    if (ws_size > 2 * A + 8)
        capw = (int)(((ws_size - 2 * A) / 8) / (size_t)N);
    if (capw > CAPW) capw = CAPW;
    if (capw < 0) capw = 0;

    k_init<<<1, 256, 0, stream>>>(esum_ws, cur_ws, N);
    k_stream<<<dim3(CH, N), NT1, 0, stream>>>(logits, temps, esum_ws, cur_ws,
                                              pairs, capw, V);
    k_select<<<N, NT, 0, stream>>>(logits, tokens, pres, freq, temps, topps,
                                   topks, V, H, out, esum_ws, cur_ws, pairs, capw);
}